// Round 9
// baseline (94.744 us; speedup 1.0000x reference)
//
#include <hip/hip_runtime.h>

// images: (B=8, H=128, W=128, C=32) f32; k=5, pad=2; out: (B,H,W,800) f32
// out[b,h,w,(kh*5+kw)*32+c] = images[b, h+kh-2, w+kw-2, c]  (0 if OOB)
//
// v9 = v8 with PLAIN stores (single-variable A/B vs NT).
// Rationale: fill kernel (plain stores) drains 6.85-6.99 TB/s; NT's
// L2-bypass path may top out lower (~5.5 effective in v8). The earlier
// v5/v6 "NT wins" A/B was on the LDS-prologue structure where plain's
// penalty is explainable by L2-thrash of the serial staging reads; v8's
// continuous-read structure has no prologue and the 16.8 MB input stays
// L3-resident regardless, so plain may reclaim the fill-path efficiency.
//
// Everything else identical to v8: 1024 blocks x 1024 threads, one output
// row per block, no LDS, no barriers, branchless clamped loads,
// XCD-chunked bijective swizzle (each XCD = one image b).

constexpr int PAD  = 2;
constexpr int CH4  = 8;                         // 32 ch = 8 float4
constexpr int HH   = 128, WW = 128, BB = 8;
constexpr int ROW_F4     = WW * CH4;            // 1024 float4 per input row
constexpr int OUT_ROW_F4 = WW * 25 * CH4;       // 25600 float4 per output row
constexpr int THREADS    = 1024;
constexpr int NWG        = BB * HH;             // 1024 blocks, 1 output row each

typedef float f32x4 __attribute__((ext_vector_type(4)));

__global__ void __launch_bounds__(THREADS) extract_patch_kernel(
        const f32x4* __restrict__ in, f32x4* __restrict__ out) {
    // XCD-chunked bijective swizzle (nwg=1024, 1024%8==0): XCD x owns
    // lin in [x*128, (x+1)*128) == image b = x.
    int bid = blockIdx.x;
    int lin = (bid & 7) * (NWG / 8) + (bid >> 3);
    int b = lin >> 7;                           // 0..7, one image per XCD
    int h = lin & (HH - 1);                     // 0..127

    int tid = threadIdx.x;
    const f32x4* img = in + (size_t)b * HH * ROW_F4;
    f32x4* rowout = out + (size_t)lin * OUT_ROW_F4;

    #pragma unroll 5
    for (int it = 0; it < OUT_ROW_F4 / THREADS; ++it) {   // 25 iters
        int j  = tid + it * THREADS;
        int w  = j / 200;                        // 200 float4 per w
        int rr = j - w * 200;
        int kq = rr >> 3;                        // kh*5+kw (0..24)
        int c4 = rr & 7;
        int kh = (kq * 205) >> 10;               // kq/5 exact for 0..24
        int kw = kq - kh * 5;
        int pc = w + kw - PAD;                   // padded col, -2..129
        int gr = h + kh - PAD;                   // padded row, -2..129
        bool ok = ((unsigned)pc < (unsigned)WW) &
                  ((unsigned)gr < (unsigned)HH);
        // Clamped address is always legal; OOB value masked to zero.
        f32x4 v = img[(size_t)(gr & (HH - 1)) * ROW_F4
                      + (pc & (WW - 1)) * CH4 + c4];
        f32x4 z = 0.f;
        v = ok ? v : z;                          // branchless padding
        rowout[j] = v;                           // PLAIN store (the A/B)
    }
}

extern "C" void kernel_launch(void* const* d_in, const int* in_sizes, int n_in,
                              void* d_out, int out_size, void* d_ws, size_t ws_size,
                              hipStream_t stream) {
    const f32x4* images = (const f32x4*)d_in[0];
    f32x4* out = (f32x4*)d_out;
    extract_patch_kernel<<<NWG, THREADS, 0, stream>>>(images, out);
}

// Round 10
// 79.514 us; speedup vs baseline: 1.1915x; 1.1915x over previous
//
#include <hip/hip_runtime.h>

// images: (B=8, H=128, W=128, C=32) f32; k=5, pad=2; out: (B,H,W,800) f32
// out[b,h,w,(kh*5+kw)*32+c] = images[b, h+kh-2, w+kw-2, c]  (0 if OOB)
//
// v10 = v8 + load-batching for MLP (single-variable change).
// v8's unroll-5 load->dep-store groups expose 5 x ~250cy L2-latency windows
// per row with only 8 waves/SIMD to cover them. Here: batch 13 independent
// loads, then 13 NT stores, then 12+12. ~2x loads in flight per wave,
// 5 -> 2 latency-exposed windows. VGPR ~76 -> ~6 waves/SIMD (store
// streaming tolerates low occupancy: fill kernel hits 6.9 TB/s at 10%).
// Everything else identical to v8 (NT stores proven: plain = +19us in v9).

constexpr int PAD  = 2;
constexpr int CH4  = 8;                         // 32 ch = 8 float4
constexpr int HH   = 128, WW = 128, BB = 8;
constexpr int ROW_F4     = WW * CH4;            // 1024 float4 per input row
constexpr int OUT_ROW_F4 = WW * 25 * CH4;       // 25600 float4 per output row
constexpr int THREADS    = 1024;
constexpr int NWG        = BB * HH;             // 1024 blocks, 1 output row each
constexpr int BATCH1     = 13;
constexpr int BATCH2     = 12;

typedef float f32x4 __attribute__((ext_vector_type(4)));

__device__ __forceinline__ f32x4 load_elem(const f32x4* __restrict__ img,
                                           int h, int j) {
    int w  = j / 200;                        // 200 float4 per w
    int rr = j - w * 200;
    int kq = rr >> 3;                        // kh*5+kw (0..24)
    int c4 = rr & 7;
    int kh = (kq * 205) >> 10;               // kq/5 exact for 0..24
    int kw = kq - kh * 5;
    int pc = w + kw - PAD;                   // padded col, -2..129
    int gr = h + kh - PAD;                   // padded row, -2..129
    bool ok = ((unsigned)pc < (unsigned)WW) &
              ((unsigned)gr < (unsigned)HH);
    f32x4 v = img[(size_t)(gr & (HH - 1)) * ROW_F4 + (pc & (WW - 1)) * CH4 + c4];
    f32x4 z = 0.f;
    return ok ? v : z;                       // branchless padding
}

__global__ void __launch_bounds__(THREADS) extract_patch_kernel(
        const f32x4* __restrict__ in, f32x4* __restrict__ out) {
    // XCD-chunked bijective swizzle (nwg=1024, 1024%8==0): XCD x owns
    // lin in [x*128, (x+1)*128) == image b = x (2.1 MB, L2-resident).
    int bid = blockIdx.x;
    int lin = (bid & 7) * (NWG / 8) + (bid >> 3);
    int b = lin >> 7;
    int h = lin & (HH - 1);

    int tid = threadIdx.x;
    const f32x4* img = in + (size_t)b * HH * ROW_F4;
    f32x4* rowout = out + (size_t)lin * OUT_ROW_F4;

    f32x4 v1[BATCH1];
    #pragma unroll
    for (int it = 0; it < BATCH1; ++it)           // 13 independent loads
        v1[it] = load_elem(img, h, tid + it * THREADS);
    #pragma unroll
    for (int it = 0; it < BATCH1; ++it)           // 13 NT stores
        __builtin_nontemporal_store(v1[it], &rowout[tid + it * THREADS]);

    f32x4 v2[BATCH2];
    #pragma unroll
    for (int it = 0; it < BATCH2; ++it)           // 12 independent loads
        v2[it] = load_elem(img, h, tid + (BATCH1 + it) * THREADS);
    #pragma unroll
    for (int it = 0; it < BATCH2; ++it)           // 12 NT stores
        __builtin_nontemporal_store(v2[it], &rowout[tid + (BATCH1 + it) * THREADS]);
}

extern "C" void kernel_launch(void* const* d_in, const int* in_sizes, int n_in,
                              void* d_out, int out_size, void* d_ws, size_t ws_size,
                              hipStream_t stream) {
    const f32x4* images = (const f32x4*)d_in[0];
    f32x4* out = (f32x4*)d_out;
    extract_patch_kernel<<<NWG, THREADS, 0, stream>>>(images, out);
}

// Round 11
// 75.850 us; speedup vs baseline: 1.2491x; 1.0483x over previous
//
#include <hip/hip_runtime.h>

// images: (B=8, H=128, W=128, C=32) f32; k=5, pad=2; out: (B,H,W,800) f32
// out[b,h,w,(kh*5+kw)*32+c] = images[b, h+kh-2, w+kw-2, c]  (0 if OOB)
//
// v11 = v8 exact revert (best: 75.8 us). v10's load-batching regressed.
// Structure: 1024 blocks x 1024 threads, one output row per block.
// No LDS, no barriers. Branchless clamped loads (L2-resident input:
// XCD-chunked swizzle gives each XCD exactly one image b, 2.1 MB < 4 MiB).
// NT stores are required: plain stores cost +19 us (v9 A/B) — the 419 MB
// write stream must bypass L2. unroll 5 is the measured sweet spot
// (5 loads in flight/wave; batch-13 in v10 cost +3.7 us).
// Combined HBM traffic ~440 MB in 75.8 us = 5.8 TB/s = 92% of the
// measured mixed-traffic ceiling (m13 copy: 6.29 TB/s) -> at roofline.

constexpr int PAD  = 2;
constexpr int CH4  = 8;                         // 32 ch = 8 float4
constexpr int HH   = 128, WW = 128, BB = 8;
constexpr int ROW_F4     = WW * CH4;            // 1024 float4 per input row
constexpr int OUT_ROW_F4 = WW * 25 * CH4;       // 25600 float4 per output row
constexpr int THREADS    = 1024;
constexpr int NWG        = BB * HH;             // 1024 blocks, 1 output row each

typedef float f32x4 __attribute__((ext_vector_type(4)));

__global__ void __launch_bounds__(THREADS) extract_patch_kernel(
        const f32x4* __restrict__ in, f32x4* __restrict__ out) {
    // XCD-chunked bijective swizzle (nwg=1024, 1024%8==0): XCD x owns
    // lin in [x*128, (x+1)*128) == image b = x.
    int bid = blockIdx.x;
    int lin = (bid & 7) * (NWG / 8) + (bid >> 3);
    int b = lin >> 7;                           // 0..7, one image per XCD
    int h = lin & (HH - 1);                     // 0..127

    int tid = threadIdx.x;
    const f32x4* img = in + (size_t)b * HH * ROW_F4;
    f32x4* rowout = out + (size_t)lin * OUT_ROW_F4;

    #pragma unroll 5
    for (int it = 0; it < OUT_ROW_F4 / THREADS; ++it) {   // 25 iters
        int j  = tid + it * THREADS;
        int w  = j / 200;                        // 200 float4 per w
        int rr = j - w * 200;
        int kq = rr >> 3;                        // kh*5+kw (0..24)
        int c4 = rr & 7;
        int kh = (kq * 205) >> 10;               // kq/5 exact for 0..24
        int kw = kq - kh * 5;
        int pc = w + kw - PAD;                   // padded col, -2..129
        int gr = h + kh - PAD;                   // padded row, -2..129
        bool ok = ((unsigned)pc < (unsigned)WW) &
                  ((unsigned)gr < (unsigned)HH);
        // Clamped address is always legal; OOB value masked to zero.
        f32x4 v = img[(size_t)(gr & (HH - 1)) * ROW_F4
                      + (pc & (WW - 1)) * CH4 + c4];
        f32x4 z = 0.f;
        v = ok ? v : z;                          // branchless padding
        __builtin_nontemporal_store(v, &rowout[j]);
    }
}

extern "C" void kernel_launch(void* const* d_in, const int* in_sizes, int n_in,
                              void* d_out, int out_size, void* d_ws, size_t ws_size,
                              hipStream_t stream) {
    const f32x4* images = (const f32x4*)d_in[0];
    f32x4* out = (f32x4*)d_out;
    extract_patch_kernel<<<NWG, THREADS, 0, stream>>>(images, out);
}